// Round 3
// baseline (4748.768 us; speedup 1.0000x reference)
//
#include <hip/hip_runtime.h>
#include <math.h>

#define NN 100000
#define EIN 800000
#define EEX 400000
#define ND 35
#define H 128
#define NG 256
#define NL 4
#define TM 8           // nodes per block in k_layer
#define TML 16         // nodes per block in k_lin_node

__device__ __forceinline__ float silu_f(float x){ return x / (1.0f + expf(-x)); }

// ---------------- lin_node: h = silu(x @ W + b), 16 nodes/block ----------------
__global__ __launch_bounds__(256) void k_lin_node(const float* __restrict__ x,
                                                  const float* __restrict__ W,
                                                  const float* __restrict__ b,
                                                  float* __restrict__ h){
  __shared__ float Ws[ND*H];      // 17.5 KB
  __shared__ float xs[TML*ND];
  const int n0 = blockIdx.x * TML;
  for (int i = threadIdx.x; i < ND*H; i += 256) Ws[i] = W[i];
  for (int i = threadIdx.x; i < TML*ND; i += 256) xs[i] = x[(size_t)n0*ND + i];
  __syncthreads();
  const int j = threadIdx.x & (H-1);
  const int half = threadIdx.x >> 7;
  const float bj = b[j];
  #pragma unroll
  for (int r = 0; r < TML/2; ++r){
    const int m = half + 2*r;
    float acc = bj;
    #pragma unroll
    for (int k = 0; k < ND; ++k) acc += xs[m*ND + k] * Ws[k*H + j];
    h[(size_t)(n0+m)*H + j] = silu_f(acc);
  }
}

// ---------------- weight transpose: Wt[j][k] = W[k][j], per (layer,mat) ----------------
__global__ void k_wtrans(const float* __restrict__ WI, const float* __restrict__ WE,
                         float* __restrict__ WtI, float* __restrict__ WtE){
  const int mat = blockIdx.x;            // 0..NL-1 intra, NL..2NL-1 inter
  const float* src; float* dst;
  if (mat < NL){ src = WI + (size_t)mat*H*H; dst = WtI + (size_t)mat*H*H; }
  else         { src = WE + (size_t)(mat-NL)*H*H; dst = WtE + (size_t)(mat-NL)*H*H; }
  for (int i = threadIdx.x; i < H*H; i += 256){
    const int j = i >> 7, k = i & (H-1);
    dst[i] = src[k*H + j];
  }
}

// ---------------- degree count ----------------
__global__ void k_count(const int* __restrict__ dst, int ne, int* __restrict__ cnt){
  int e = blockIdx.x*256 + threadIdx.x;
  if (e < ne) atomicAdd(&cnt[dst[e]], 1);
}

// ---------------- 2-level exclusive scan over N counts ----------------
__global__ void k_block_sum(const int* __restrict__ cnt, int n, int* __restrict__ bsum){
  __shared__ int s[256];
  int i = blockIdx.x*256 + threadIdx.x;
  s[threadIdx.x] = (i < n) ? cnt[i] : 0;
  __syncthreads();
  for (int o = 128; o > 0; o >>= 1){
    if (threadIdx.x < o) s[threadIdx.x] += s[threadIdx.x + o];
    __syncthreads();
  }
  if (threadIdx.x == 0) bsum[blockIdx.x] = s[0];
}
__global__ void k_scan_top(int* __restrict__ bsum, int nb){
  __shared__ int s[512];
  int t = threadIdx.x;
  int v = (t < nb) ? bsum[t] : 0;
  s[t] = v; __syncthreads();
  for (int o = 1; o < 512; o <<= 1){
    int a = (t >= o) ? s[t-o] : 0;
    __syncthreads();
    s[t] += a;
    __syncthreads();
  }
  if (t < nb) bsum[t] = s[t] - v;   // exclusive
}
__global__ void k_scan_write(const int* __restrict__ cnt, const int* __restrict__ bsum,
                             int n, int* __restrict__ rowp, int* __restrict__ cur){
  __shared__ int s[256];
  int t = threadIdx.x, i = blockIdx.x*256 + t;
  int v = (i < n) ? cnt[i] : 0;
  s[t] = v; __syncthreads();
  for (int o = 1; o < 256; o <<= 1){
    int a = (t >= o) ? s[t-o] : 0;
    __syncthreads();
    s[t] += a;
    __syncthreads();
  }
  if (i < n){
    int ex = bsum[blockIdx.x] + s[t] - v;
    rowp[i] = ex; cur[i] = ex;
  }
}

// ---------------- CSR fill ----------------
__global__ void k_fill_intra(const int* __restrict__ src, const int* __restrict__ dst,
                             const float* __restrict__ ea,
                             int* __restrict__ cur, int* __restrict__ col, float* __restrict__ val){
  int e = blockIdx.x*256 + threadIdx.x;
  if (e < EIN){
    int d = dst[e];
    int slot = atomicAdd(&cur[d], 1);
    col[slot] = src[e];
    val[slot] = ea[e];
  }
}
__global__ void k_fill_inter(const int* __restrict__ src, const int* __restrict__ dst,
                             const float* __restrict__ pos,
                             int* __restrict__ cur, int* __restrict__ col, float* __restrict__ val){
  int e = blockIdx.x*256 + threadIdx.x;
  if (e < EEX){
    int s = src[e], d = dst[e];
    float dx = pos[3*s+0] - pos[3*d+0];
    float dy = pos[3*s+1] - pos[3*d+1];
    float dz = pos[3*s+2] - pos[3*d+2];
    float w = expf(-(dx*dx + dy*dy + dz*dz));
    int slot = atomicAdd(&cur[d], 1);
    col[slot] = s;
    val[slot] = w;
  }
}

// ---------------- fused layer: gather -> matmul -> norm/silu/state update ----------------
__global__ __launch_bounds__(256) void k_layer(
    const float* __restrict__ hin, float* __restrict__ hout,
    float* __restrict__ vp, float* __restrict__ vl,
    const int* __restrict__ rowI, const int* __restrict__ cntI,
    const int* __restrict__ colI, const float* __restrict__ valI,
    const int* __restrict__ rowE, const int* __restrict__ cntE,
    const int* __restrict__ colE, const float* __restrict__ valE,
    const float* __restrict__ WtI, const float* __restrict__ bI,   // Wt: [j][k]
    const float* __restrict__ WtE, const float* __restrict__ bE)
{
  __shared__ float aggI[TM][H];
  __shared__ float aggE[TM][H];
  const int n0 = blockIdx.x * TM;

  // ---- gather phase: thread = (slot 0..7 -> node, lane 0..31 -> float4 chans), 4-way unroll ----
  {
    const int slot = threadIdx.x >> 5;
    const int lane = threadIdx.x & 31;
    const int j4 = lane * 4;
    const int n = n0 + slot;

    float ax=0.f, ay=0.f, az=0.f, aw=0.f;
    {
      const int s = rowI[n], c = cntI[n];
      int t = 0;
      for (; t + 4 <= c; t += 4){
        const int c0 = colI[s+t],   c1 = colI[s+t+1];
        const int c2 = colI[s+t+2], c3 = colI[s+t+3];
        const float v0 = valI[s+t],   v1 = valI[s+t+1];
        const float v2 = valI[s+t+2], v3 = valI[s+t+3];
        const float4 h0 = *(const float4*)(hin + (size_t)c0*H + j4);
        const float4 h1 = *(const float4*)(hin + (size_t)c1*H + j4);
        const float4 h2 = *(const float4*)(hin + (size_t)c2*H + j4);
        const float4 h3 = *(const float4*)(hin + (size_t)c3*H + j4);
        ax += h0.x*v0 + h1.x*v1 + h2.x*v2 + h3.x*v3;
        ay += h0.y*v0 + h1.y*v1 + h2.y*v2 + h3.y*v3;
        az += h0.z*v0 + h1.z*v1 + h2.z*v2 + h3.z*v3;
        aw += h0.w*v0 + h1.w*v1 + h2.w*v2 + h3.w*v3;
      }
      for (; t < c; ++t){
        const int c0 = colI[s+t];
        const float v0 = valI[s+t];
        const float4 h0 = *(const float4*)(hin + (size_t)c0*H + j4);
        ax += h0.x*v0; ay += h0.y*v0; az += h0.z*v0; aw += h0.w*v0;
      }
      *(float4*)&aggI[slot][j4] = make_float4(ax, ay, az, aw);
    }
    ax=0.f; ay=0.f; az=0.f; aw=0.f;
    {
      const int s = rowE[n], c = cntE[n];
      int t = 0;
      for (; t + 4 <= c; t += 4){
        const int c0 = colE[s+t],   c1 = colE[s+t+1];
        const int c2 = colE[s+t+2], c3 = colE[s+t+3];
        const float v0 = valE[s+t],   v1 = valE[s+t+1];
        const float v2 = valE[s+t+2], v3 = valE[s+t+3];
        const float4 h0 = *(const float4*)(hin + (size_t)c0*H + j4);
        const float4 h1 = *(const float4*)(hin + (size_t)c1*H + j4);
        const float4 h2 = *(const float4*)(hin + (size_t)c2*H + j4);
        const float4 h3 = *(const float4*)(hin + (size_t)c3*H + j4);
        ax += h0.x*v0 + h1.x*v1 + h2.x*v2 + h3.x*v3;
        ay += h0.y*v0 + h1.y*v1 + h2.y*v2 + h3.y*v3;
        az += h0.z*v0 + h1.z*v1 + h2.z*v2 + h3.z*v3;
        aw += h0.w*v0 + h1.w*v1 + h2.w*v2 + h3.w*v3;
      }
      for (; t < c; ++t){
        const int c0 = colE[s+t];
        const float v0 = valE[s+t];
        const float4 h0 = *(const float4*)(hin + (size_t)c0*H + j4);
        ax += h0.x*v0; ay += h0.y*v0; az += h0.z*v0; aw += h0.w*v0;
      }
      *(float4*)&aggE[slot][j4] = make_float4(ax, ay, az, aw);
    }
  }
  __syncthreads();

  // ---- matmul phase: thread = (j0 0..63, q 0..3 wave-uniform); 2 nodes x 2 cols ----
  const int j0 = threadIdx.x & 63;
  const int q  = threadIdx.x >> 6;
  float accI[2][2], accE[2][2];
  #pragma unroll
  for (int r = 0; r < 2; ++r){ accI[r][0]=accI[r][1]=accE[r][0]=accE[r][1]=0.f; }

  const float* wtI0p = WtI + (size_t)j0*H;
  const float* wtI1p = WtI + (size_t)(j0+64)*H;
  const float* wtE0p = WtE + (size_t)j0*H;
  const float* wtE1p = WtE + (size_t)(j0+64)*H;

  for (int kk = 0; kk < H; kk += 4){
    const float4 wI0 = *(const float4*)(wtI0p + kk);
    const float4 wI1 = *(const float4*)(wtI1p + kk);
    const float4 wE0 = *(const float4*)(wtE0p + kk);
    const float4 wE1 = *(const float4*)(wtE1p + kk);
    float aIb[2][4], aEb[2][4];
    #pragma unroll
    for (int r = 0; r < 2; ++r){
      const int m = q + 4*r;
      *(float4*)aIb[r] = *(const float4*)&aggI[m][kk];   // wave-uniform addr: LDS broadcast
      *(float4*)aEb[r] = *(const float4*)&aggE[m][kk];
    }
    #pragma unroll
    for (int r = 0; r < 2; ++r){
      accI[r][0] += aIb[r][0]*wI0.x + aIb[r][1]*wI0.y + aIb[r][2]*wI0.z + aIb[r][3]*wI0.w;
      accI[r][1] += aIb[r][0]*wI1.x + aIb[r][1]*wI1.y + aIb[r][2]*wI1.z + aIb[r][3]*wI1.w;
      accE[r][0] += aEb[r][0]*wE0.x + aEb[r][1]*wE0.y + aEb[r][2]*wE0.z + aEb[r][3]*wE0.w;
      accE[r][1] += aEb[r][0]*wE1.x + aEb[r][1]*wE1.y + aEb[r][2]*wE1.z + aEb[r][3]*wE1.w;
    }
  }

  // ---- epilogue (vp/vl are streaming: non-temporal to keep hin resident in L3) ----
  #pragma unroll
  for (int r = 0; r < 2; ++r){
    const int m = q + 4*r;
    const int n = n0 + m;
    const float cI = (float)cntI[n];
    const float cE = (float)cntE[n];
    const float rdI = 1.0f / (cI + 1.0f);
    const float ldE = logf(cE + 1.0f);
    #pragma unroll
    for (int c2 = 0; c2 < 2; ++c2){
      const int j = j0 + 64*c2;
      const float mi = (accI[r][c2] + cI*bI[j]) * rdI;
      const float me = (accE[r][c2] + cE*bE[j]) * ldE;
      const size_t idx = (size_t)n*H + j;
      const float vpo = __builtin_nontemporal_load(&vp[idx]);
      const float vlo = __builtin_nontemporal_load(&vl[idx]);
      const float vpn = silu_f(mi + vpo);
      const float vln = silu_f(me + vlo);
      __builtin_nontemporal_store(vpn, &vp[idx]);
      __builtin_nontemporal_store(vln, &vl[idx]);
      hout[idx] = hin[idx] + vpn + vln;
    }
  }
}

// ---------------- pool: batch is sorted; register-accumulate, flush on boundary ----------------
__global__ void k_pool(const float* __restrict__ h, const int* __restrict__ batch,
                       float* __restrict__ g){
  const int j = threadIdx.x;
  const int n0 = blockIdx.x * 64;
  int nend = n0 + 64; if (nend > NN) nend = NN;
  float acc = 0.f;
  int cur = batch[n0];
  for (int n = n0; n < nend; ++n){
    int b = batch[n];
    if (b != cur){
      atomicAdd(&g[(size_t)cur*H + j], acc);
      acc = 0.f; cur = b;
    }
    acc += h[(size_t)n*H + j];
  }
  atomicAdd(&g[(size_t)cur*H + j], acc);
}

// ---------------- FC head: per-graph-row independent ----------------
__global__ void k_fc(const float* __restrict__ g, const float* __restrict__ fcW,
                     const float* __restrict__ fcb, const float* __restrict__ gamma,
                     const float* __restrict__ beta, const float* __restrict__ outW,
                     const float* __restrict__ outb, float* __restrict__ out){
  __shared__ float row[H];
  __shared__ float red[H];
  const int gi = blockIdx.x;
  const int j = threadIdx.x;
  row[j] = g[(size_t)gi*H + j];
  __syncthreads();
  const float bn_scale = rsqrtf(1.0f + 1e-5f);
  for (int l = 0; l < 3; ++l){
    const float* W = fcW + (size_t)l*H*H;
    float acc = fcb[l*H + j];
    #pragma unroll 8
    for (int k = 0; k < H; ++k) acc += row[k] * W[k*H + j];
    acc = (acc > 0.f) ? acc : 0.01f*acc;             // leaky_relu
    acc = acc * bn_scale * gamma[l*H + j] + beta[l*H + j];
    __syncthreads();
    row[j] = acc;
    __syncthreads();
  }
  red[j] = row[j] * outW[j];
  __syncthreads();
  for (int o = 64; o > 0; o >>= 1){
    if (j < o) red[j] += red[j + o];
    __syncthreads();
  }
  if (j == 0) out[gi] = red[0] + outb[0];
}

extern "C" void kernel_launch(void* const* d_in, const int* in_sizes, int n_in,
                              void* d_out, int out_size, void* d_ws, size_t ws_size,
                              hipStream_t stream)
{
  const float* x    = (const float*)d_in[0];
  const int*   eii  = (const int*)  d_in[1];
  const int*   eie  = (const int*)  d_in[2];
  const float* pos  = (const float*)d_in[3];
  const float* ea   = (const float*)d_in[4];
  const int*   batch= (const int*)  d_in[5];
  const float* lnW  = (const float*)d_in[6];
  const float* lnb  = (const float*)d_in[7];
  const float* WIa  = (const float*)d_in[8];
  const float* bIa  = (const float*)d_in[9];
  const float* WEa  = (const float*)d_in[10];
  const float* bEa  = (const float*)d_in[11];
  const float* fcW  = (const float*)d_in[12];
  const float* fcb  = (const float*)d_in[13];
  const float* gam  = (const float*)d_in[14];
  const float* bet  = (const float*)d_in[15];
  const float* outW = (const float*)d_in[16];
  const float* outb = (const float*)d_in[17];
  float* out = (float*)d_out;

  const int* src_i = eii;  const int* dst_i = eii + EIN;
  const int* src_e = eie;  const int* dst_e = eie + EEX;

  const size_t NH = (size_t)NN * H;
  float* hA = (float*)d_ws;
  float* hB = hA + NH;
  float* vp = hB + NH;
  float* vl = vp + NH;
  float* gp = vl + NH;                     // NG*H
  int* cnt_i = (int*)(gp + (size_t)NG*H);  // NN
  int* cnt_e = cnt_i + NN;
  int* row_i = cnt_e + NN;
  int* row_e = row_i + NN;
  int* cur_i = row_e + NN;
  int* cur_e = cur_i + NN;
  int* col_i = cur_e + NN;                 // EIN
  float* val_i = (float*)(col_i + EIN);    // EIN
  int* col_e = (int*)(val_i + EIN);        // EEX
  float* val_e = (float*)(col_e + EEX);    // EEX
  int* bsum = (int*)(val_e + EEX);         // 1024
  float* WtI = (float*)(bsum + 1024);      // NL*H*H
  float* WtE = WtI + (size_t)NL*H*H;       // NL*H*H

  const size_t need = (4*NH + (size_t)NG*H + 6*(size_t)NN + 2*(size_t)EIN + 2*(size_t)EEX
                       + 1024 + 2*(size_t)NL*H*H)*4;
  if (ws_size < need) return;

  // zero: vp+vl (contiguous), gp+cnt_i+cnt_e (contiguous)
  hipMemsetAsync(vp, 0, 2*NH*sizeof(float), stream);
  hipMemsetAsync(gp, 0, (size_t)NG*H*sizeof(float) + 2*(size_t)NN*sizeof(int), stream);

  k_wtrans<<<2*NL, 256, 0, stream>>>(WIa, WEa, WtI, WtE);
  k_lin_node<<<NN/TML, 256, 0, stream>>>(x, lnW, lnb, hA);

  k_count<<<(EIN+255)/256, 256, 0, stream>>>(dst_i, EIN, cnt_i);
  k_count<<<(EEX+255)/256, 256, 0, stream>>>(dst_e, EEX, cnt_e);

  const int NB = (NN + 255)/256;  // 391 <= 512
  k_block_sum<<<NB, 256, 0, stream>>>(cnt_i, NN, bsum);
  k_scan_top<<<1, 512, 0, stream>>>(bsum, NB);
  k_scan_write<<<NB, 256, 0, stream>>>(cnt_i, bsum, NN, row_i, cur_i);
  k_block_sum<<<NB, 256, 0, stream>>>(cnt_e, NN, bsum);
  k_scan_top<<<1, 512, 0, stream>>>(bsum, NB);
  k_scan_write<<<NB, 256, 0, stream>>>(cnt_e, bsum, NN, row_e, cur_e);

  k_fill_intra<<<(EIN+255)/256, 256, 0, stream>>>(src_i, dst_i, ea, cur_i, col_i, val_i);
  k_fill_inter<<<(EEX+255)/256, 256, 0, stream>>>(src_e, dst_e, pos, cur_e, col_e, val_e);

  const float* hin = hA; float* hout = hB;
  for (int l = 0; l < NL; ++l){
    k_layer<<<NN/TM, 256, 0, stream>>>(hin, hout, vp, vl,
        row_i, cnt_i, col_i, val_i,
        row_e, cnt_e, col_e, val_e,
        WtI + (size_t)l*H*H, bIa + (size_t)l*H,
        WtE + (size_t)l*H*H, bEa + (size_t)l*H);
    float* t = (float*)hin; hin = hout; hout = t;
  }
  // after 4 swaps final h is back in hA == hin

  k_pool<<<(NN+63)/64, H, 0, stream>>>(hin, batch, gp);
  k_fc<<<NG, H, 0, stream>>>(gp, fcW, fcb, gam, bet, outW, outb, out);
}

// Round 4
// 1402.523 us; speedup vs baseline: 3.3859x; 3.3859x over previous
//
#include <hip/hip_runtime.h>
#include <math.h>

#define NN 100000
#define EIN 800000
#define EEX 400000
#define ND 35
#define H 128
#define NG 256
#define NL 4
#define TM 8           // nodes per block in k_layer
#define TML 16         // nodes per block in k_lin_node

__device__ __forceinline__ float silu_f(float x){ return x / (1.0f + expf(-x)); }

// ---------------- lin_node: h = silu(x @ W + b), 16 nodes/block ----------------
__global__ __launch_bounds__(256) void k_lin_node(const float* __restrict__ x,
                                                  const float* __restrict__ W,
                                                  const float* __restrict__ b,
                                                  float* __restrict__ h){
  __shared__ float Ws[ND*H];      // 17.5 KB
  __shared__ float xs[TML*ND];
  const int n0 = blockIdx.x * TML;
  for (int i = threadIdx.x; i < ND*H; i += 256) Ws[i] = W[i];
  for (int i = threadIdx.x; i < TML*ND; i += 256) xs[i] = x[(size_t)n0*ND + i];
  __syncthreads();
  const int j = threadIdx.x & (H-1);
  const int half = threadIdx.x >> 7;
  const float bj = b[j];
  #pragma unroll
  for (int r = 0; r < TML/2; ++r){
    const int m = half + 2*r;
    float acc = bj;
    #pragma unroll
    for (int k = 0; k < ND; ++k) acc += xs[m*ND + k] * Ws[k*H + j];
    h[(size_t)(n0+m)*H + j] = silu_f(acc);
  }
}

// ---------------- degree count ----------------
__global__ void k_count(const int* __restrict__ dst, int ne, int* __restrict__ cnt){
  int e = blockIdx.x*256 + threadIdx.x;
  if (e < ne) atomicAdd(&cnt[dst[e]], 1);
}

// ---------------- 2-level exclusive scan over N counts ----------------
__global__ void k_block_sum(const int* __restrict__ cnt, int n, int* __restrict__ bsum){
  __shared__ int s[256];
  int i = blockIdx.x*256 + threadIdx.x;
  s[threadIdx.x] = (i < n) ? cnt[i] : 0;
  __syncthreads();
  for (int o = 128; o > 0; o >>= 1){
    if (threadIdx.x < o) s[threadIdx.x] += s[threadIdx.x + o];
    __syncthreads();
  }
  if (threadIdx.x == 0) bsum[blockIdx.x] = s[0];
}
__global__ void k_scan_top(int* __restrict__ bsum, int nb){
  __shared__ int s[512];
  int t = threadIdx.x;
  int v = (t < nb) ? bsum[t] : 0;
  s[t] = v; __syncthreads();
  for (int o = 1; o < 512; o <<= 1){
    int a = (t >= o) ? s[t-o] : 0;
    __syncthreads();
    s[t] += a;
    __syncthreads();
  }
  if (t < nb) bsum[t] = s[t] - v;   // exclusive
}
__global__ void k_scan_write(const int* __restrict__ cnt, const int* __restrict__ bsum,
                             int n, int* __restrict__ rowp, int* __restrict__ cur){
  __shared__ int s[256];
  int t = threadIdx.x, i = blockIdx.x*256 + t;
  int v = (i < n) ? cnt[i] : 0;
  s[t] = v; __syncthreads();
  for (int o = 1; o < 256; o <<= 1){
    int a = (t >= o) ? s[t-o] : 0;
    __syncthreads();
    s[t] += a;
    __syncthreads();
  }
  if (i < n){
    int ex = bsum[blockIdx.x] + s[t] - v;
    rowp[i] = ex; cur[i] = ex;
  }
}

// ---------------- CSR fill ----------------
__global__ void k_fill_intra(const int* __restrict__ src, const int* __restrict__ dst,
                             const float* __restrict__ ea,
                             int* __restrict__ cur, int* __restrict__ col, float* __restrict__ val){
  int e = blockIdx.x*256 + threadIdx.x;
  if (e < EIN){
    int d = dst[e];
    int slot = atomicAdd(&cur[d], 1);
    col[slot] = src[e];
    val[slot] = ea[e];
  }
}
__global__ void k_fill_inter(const int* __restrict__ src, const int* __restrict__ dst,
                             const float* __restrict__ pos,
                             int* __restrict__ cur, int* __restrict__ col, float* __restrict__ val){
  int e = blockIdx.x*256 + threadIdx.x;
  if (e < EEX){
    int s = src[e], d = dst[e];
    float dx = pos[3*s+0] - pos[3*d+0];
    float dy = pos[3*s+1] - pos[3*d+1];
    float dz = pos[3*s+2] - pos[3*d+2];
    float w = expf(-(dx*dx + dy*dy + dz*dz));
    int slot = atomicAdd(&cur[d], 1);
    col[slot] = s;
    val[slot] = w;
  }
}

// ---------------- fused layer: gather -> matmul -> norm/silu/state update ----------------
// Gather: thread = (slot 0..7 -> node, lane 0..31 -> float4 chans).
// 8-way unrolled edge loop: 8 broadcast col/val loads, then 8 independent
// float4 gathers in flight, then FMAs. 4-way + scalar tails.
__global__ __launch_bounds__(256) void k_layer(
    const float* __restrict__ hin, float* __restrict__ hout,
    float* __restrict__ vp, float* __restrict__ vl,
    const int* __restrict__ rowI, const int* __restrict__ cntI,
    const int* __restrict__ colI, const float* __restrict__ valI,
    const int* __restrict__ rowE, const int* __restrict__ cntE,
    const int* __restrict__ colE, const float* __restrict__ valE,
    const float* __restrict__ WI, const float* __restrict__ bI,   // W: [k][j]
    const float* __restrict__ WE, const float* __restrict__ bE)
{
  __shared__ float aggI[TM][H];
  __shared__ float aggE[TM][H];
  const int n0 = blockIdx.x * TM;

  // ---- gather phase ----
  {
    const int slot = threadIdx.x >> 5;
    const int lane = threadIdx.x & 31;
    const int j4 = lane * 4;
    const int n = n0 + slot;

    #pragma unroll
    for (int list = 0; list < 2; ++list){
      const int*   rowp = list ? rowE : rowI;
      const int*   cntp = list ? cntE : cntI;
      const int*   colp = list ? colE : colI;
      const float* valp = list ? valE : valI;
      float ax=0.f, ay=0.f, az=0.f, aw=0.f;
      const int s = rowp[n], c = cntp[n];
      int t = 0;
      for (; t + 8 <= c; t += 8){
        int cc[8]; float vv[8];
        #pragma unroll
        for (int u = 0; u < 8; ++u){ cc[u] = colp[s+t+u]; vv[u] = valp[s+t+u]; }
        float4 hh[8];
        #pragma unroll
        for (int u = 0; u < 8; ++u) hh[u] = *(const float4*)(hin + (size_t)cc[u]*H + j4);
        #pragma unroll
        for (int u = 0; u < 8; ++u){
          ax += hh[u].x*vv[u]; ay += hh[u].y*vv[u];
          az += hh[u].z*vv[u]; aw += hh[u].w*vv[u];
        }
      }
      for (; t + 4 <= c; t += 4){
        int cc[4]; float vv[4];
        #pragma unroll
        for (int u = 0; u < 4; ++u){ cc[u] = colp[s+t+u]; vv[u] = valp[s+t+u]; }
        float4 hh[4];
        #pragma unroll
        for (int u = 0; u < 4; ++u) hh[u] = *(const float4*)(hin + (size_t)cc[u]*H + j4);
        #pragma unroll
        for (int u = 0; u < 4; ++u){
          ax += hh[u].x*vv[u]; ay += hh[u].y*vv[u];
          az += hh[u].z*vv[u]; aw += hh[u].w*vv[u];
        }
      }
      for (; t < c; ++t){
        const int c0 = colp[s+t];
        const float v0 = valp[s+t];
        const float4 h0 = *(const float4*)(hin + (size_t)c0*H + j4);
        ax += h0.x*v0; ay += h0.y*v0; az += h0.z*v0; aw += h0.w*v0;
      }
      if (list) *(float4*)&aggE[slot][j4] = make_float4(ax, ay, az, aw);
      else      *(float4*)&aggI[slot][j4] = make_float4(ax, ay, az, aw);
    }
  }
  __syncthreads();

  // ---- matmul phase: thread = (j0 0..63, q 0..3 wave-uniform); 2 nodes x 2 cols ----
  // Weight loads W[k*H+j0]: 64 consecutive lanes -> fully coalesced, L1/L2-resident.
  const int j0 = threadIdx.x & 63;
  const int q  = threadIdx.x >> 6;
  float accI[2][2], accE[2][2];
  #pragma unroll
  for (int r = 0; r < 2; ++r){ accI[r][0]=accI[r][1]=accE[r][0]=accE[r][1]=0.f; }

  for (int kk = 0; kk < H; kk += 4){
    float aIb[2][4], aEb[2][4];
    #pragma unroll
    for (int r = 0; r < 2; ++r){
      const int m = q + 4*r;
      *(float4*)aIb[r] = *(const float4*)&aggI[m][kk];   // wave-uniform addr: LDS broadcast
      *(float4*)aEb[r] = *(const float4*)&aggE[m][kk];
    }
    #pragma unroll
    for (int k2 = 0; k2 < 4; ++k2){
      const int k = kk + k2;
      const float wi0 = WI[k*H + j0];
      const float wi1 = WI[k*H + j0 + 64];
      const float we0 = WE[k*H + j0];
      const float we1 = WE[k*H + j0 + 64];
      #pragma unroll
      for (int r = 0; r < 2; ++r){
        accI[r][0] += aIb[r][k2]*wi0;
        accI[r][1] += aIb[r][k2]*wi1;
        accE[r][0] += aEb[r][k2]*we0;
        accE[r][1] += aEb[r][k2]*we1;
      }
    }
  }

  // ---- epilogue ----
  #pragma unroll
  for (int r = 0; r < 2; ++r){
    const int m = q + 4*r;
    const int n = n0 + m;
    const float cI = (float)cntI[n];
    const float cE = (float)cntE[n];
    const float rdI = 1.0f / (cI + 1.0f);
    const float ldE = logf(cE + 1.0f);
    #pragma unroll
    for (int c2 = 0; c2 < 2; ++c2){
      const int j = j0 + 64*c2;
      const float mi = (accI[r][c2] + cI*bI[j]) * rdI;
      const float me = (accE[r][c2] + cE*bE[j]) * ldE;
      const size_t idx = (size_t)n*H + j;
      const float vpn = silu_f(mi + vp[idx]);
      const float vln = silu_f(me + vl[idx]);
      vp[idx] = vpn; vl[idx] = vln;
      hout[idx] = hin[idx] + vpn + vln;
    }
  }
}

// ---------------- pool: batch is sorted; register-accumulate, flush on boundary ----------------
__global__ void k_pool(const float* __restrict__ h, const int* __restrict__ batch,
                       float* __restrict__ g){
  const int j = threadIdx.x;
  const int n0 = blockIdx.x * 64;
  int nend = n0 + 64; if (nend > NN) nend = NN;
  float acc = 0.f;
  int cur = batch[n0];
  for (int n = n0; n < nend; ++n){
    int b = batch[n];
    if (b != cur){
      atomicAdd(&g[(size_t)cur*H + j], acc);
      acc = 0.f; cur = b;
    }
    acc += h[(size_t)n*H + j];
  }
  atomicAdd(&g[(size_t)cur*H + j], acc);
}

// ---------------- FC head: per-graph-row independent ----------------
__global__ void k_fc(const float* __restrict__ g, const float* __restrict__ fcW,
                     const float* __restrict__ fcb, const float* __restrict__ gamma,
                     const float* __restrict__ beta, const float* __restrict__ outW,
                     const float* __restrict__ outb, float* __restrict__ out){
  __shared__ float row[H];
  __shared__ float red[H];
  const int gi = blockIdx.x;
  const int j = threadIdx.x;
  row[j] = g[(size_t)gi*H + j];
  __syncthreads();
  const float bn_scale = rsqrtf(1.0f + 1e-5f);
  for (int l = 0; l < 3; ++l){
    const float* W = fcW + (size_t)l*H*H;
    float acc = fcb[l*H + j];
    #pragma unroll 8
    for (int k = 0; k < H; ++k) acc += row[k] * W[k*H + j];
    acc = (acc > 0.f) ? acc : 0.01f*acc;             // leaky_relu
    acc = acc * bn_scale * gamma[l*H + j] + beta[l*H + j];
    __syncthreads();
    row[j] = acc;
    __syncthreads();
  }
  red[j] = row[j] * outW[j];
  __syncthreads();
  for (int o = 64; o > 0; o >>= 1){
    if (j < o) red[j] += red[j + o];
    __syncthreads();
  }
  if (j == 0) out[gi] = red[0] + outb[0];
}

extern "C" void kernel_launch(void* const* d_in, const int* in_sizes, int n_in,
                              void* d_out, int out_size, void* d_ws, size_t ws_size,
                              hipStream_t stream)
{
  const float* x    = (const float*)d_in[0];
  const int*   eii  = (const int*)  d_in[1];
  const int*   eie  = (const int*)  d_in[2];
  const float* pos  = (const float*)d_in[3];
  const float* ea   = (const float*)d_in[4];
  const int*   batch= (const int*)  d_in[5];
  const float* lnW  = (const float*)d_in[6];
  const float* lnb  = (const float*)d_in[7];
  const float* WIa  = (const float*)d_in[8];
  const float* bIa  = (const float*)d_in[9];
  const float* WEa  = (const float*)d_in[10];
  const float* bEa  = (const float*)d_in[11];
  const float* fcW  = (const float*)d_in[12];
  const float* fcb  = (const float*)d_in[13];
  const float* gam  = (const float*)d_in[14];
  const float* bet  = (const float*)d_in[15];
  const float* outW = (const float*)d_in[16];
  const float* outb = (const float*)d_in[17];
  float* out = (float*)d_out;

  const int* src_i = eii;  const int* dst_i = eii + EIN;
  const int* src_e = eie;  const int* dst_e = eie + EEX;

  const size_t NH = (size_t)NN * H;
  float* hA = (float*)d_ws;
  float* hB = hA + NH;
  float* vp = hB + NH;
  float* vl = vp + NH;
  float* gp = vl + NH;                     // NG*H
  int* cnt_i = (int*)(gp + (size_t)NG*H);  // NN
  int* cnt_e = cnt_i + NN;
  int* row_i = cnt_e + NN;
  int* row_e = row_i + NN;
  int* cur_i = row_e + NN;
  int* cur_e = cur_i + NN;
  int* col_i = cur_e + NN;                 // EIN
  float* val_i = (float*)(col_i + EIN);    // EIN
  int* col_e = (int*)(val_i + EIN);        // EEX
  float* val_e = (float*)(col_e + EEX);    // EEX
  int* bsum = (int*)(val_e + EEX);         // 1024

  const size_t need = (4*NH + (size_t)NG*H + 6*(size_t)NN + 2*(size_t)EIN + 2*(size_t)EEX + 1024)*4;
  if (ws_size < need) return;

  // zero: vp+vl (contiguous), gp+cnt_i+cnt_e (contiguous)
  hipMemsetAsync(vp, 0, 2*NH*sizeof(float), stream);
  hipMemsetAsync(gp, 0, (size_t)NG*H*sizeof(float) + 2*(size_t)NN*sizeof(int), stream);

  k_lin_node<<<NN/TML, 256, 0, stream>>>(x, lnW, lnb, hA);

  k_count<<<(EIN+255)/256, 256, 0, stream>>>(dst_i, EIN, cnt_i);
  k_count<<<(EEX+255)/256, 256, 0, stream>>>(dst_e, EEX, cnt_e);

  const int NB = (NN + 255)/256;  // 391 <= 512
  k_block_sum<<<NB, 256, 0, stream>>>(cnt_i, NN, bsum);
  k_scan_top<<<1, 512, 0, stream>>>(bsum, NB);
  k_scan_write<<<NB, 256, 0, stream>>>(cnt_i, bsum, NN, row_i, cur_i);
  k_block_sum<<<NB, 256, 0, stream>>>(cnt_e, NN, bsum);
  k_scan_top<<<1, 512, 0, stream>>>(bsum, NB);
  k_scan_write<<<NB, 256, 0, stream>>>(cnt_e, bsum, NN, row_e, cur_e);

  k_fill_intra<<<(EIN+255)/256, 256, 0, stream>>>(src_i, dst_i, ea, cur_i, col_i, val_i);
  k_fill_inter<<<(EEX+255)/256, 256, 0, stream>>>(src_e, dst_e, pos, cur_e, col_e, val_e);

  const float* hin = hA; float* hout = hB;
  for (int l = 0; l < NL; ++l){
    k_layer<<<NN/TM, 256, 0, stream>>>(hin, hout, vp, vl,
        row_i, cnt_i, col_i, val_i,
        row_e, cnt_e, col_e, val_e,
        WIa + (size_t)l*H*H, bIa + (size_t)l*H,
        WEa + (size_t)l*H*H, bEa + (size_t)l*H);
    float* t = (float*)hin; hin = hout; hout = t;
  }
  // after 4 swaps final h is back in hA == hin

  k_pool<<<(NN+63)/64, H, 0, stream>>>(hin, batch, gp);
  k_fc<<<NG, H, 0, stream>>>(gp, fcW, fcb, gam, bet, outW, outb, out);
}

// Round 5
// 1335.470 us; speedup vs baseline: 3.5559x; 1.0502x over previous
//
#include <hip/hip_runtime.h>
#include <math.h>

#define NN 100000
#define EIN 800000
#define EEX 400000
#define ND 35
#define H 128
#define NG 256
#define NL 4
#define TM 8           // nodes per block in k_layer
#define TML 16         // nodes per block in k_lin_node

typedef unsigned short u16;

__device__ __forceinline__ float silu_f(float x){ return x / (1.0f + expf(-x)); }
__device__ __forceinline__ float bf2f(u16 v){ return __uint_as_float(((unsigned)v) << 16); }
__device__ __forceinline__ u16 f2bf(float f){
  unsigned u = __float_as_uint(f);
  u += 0x7FFFu + ((u >> 16) & 1u);   // RNE
  return (u16)(u >> 16);
}

// ---------------- lin_node: h = silu(x @ W + b) -> bf16 ----------------
__global__ __launch_bounds__(256) void k_lin_node(const float* __restrict__ x,
                                                  const float* __restrict__ W,
                                                  const float* __restrict__ b,
                                                  u16* __restrict__ h){
  __shared__ float Ws[ND*H];      // 17.5 KB
  __shared__ float xs[TML*ND];
  const int n0 = blockIdx.x * TML;
  for (int i = threadIdx.x; i < ND*H; i += 256) Ws[i] = W[i];
  for (int i = threadIdx.x; i < TML*ND; i += 256) xs[i] = x[(size_t)n0*ND + i];
  __syncthreads();
  const int j = threadIdx.x & (H-1);
  const int half = threadIdx.x >> 7;
  const float bj = b[j];
  #pragma unroll
  for (int r = 0; r < TML/2; ++r){
    const int m = half + 2*r;
    float acc = bj;
    #pragma unroll
    for (int k = 0; k < ND; ++k) acc += xs[m*ND + k] * Ws[k*H + j];
    h[(size_t)(n0+m)*H + j] = f2bf(silu_f(acc));
  }
}

// ---------------- degree count ----------------
__global__ void k_count(const int* __restrict__ dst, int ne, int* __restrict__ cnt){
  int e = blockIdx.x*256 + threadIdx.x;
  if (e < ne) atomicAdd(&cnt[dst[e]], 1);
}

// ---------------- 2-level exclusive scan over N counts ----------------
__global__ void k_block_sum(const int* __restrict__ cnt, int n, int* __restrict__ bsum){
  __shared__ int s[256];
  int i = blockIdx.x*256 + threadIdx.x;
  s[threadIdx.x] = (i < n) ? cnt[i] : 0;
  __syncthreads();
  for (int o = 128; o > 0; o >>= 1){
    if (threadIdx.x < o) s[threadIdx.x] += s[threadIdx.x + o];
    __syncthreads();
  }
  if (threadIdx.x == 0) bsum[blockIdx.x] = s[0];
}
__global__ void k_scan_top(int* __restrict__ bsum, int nb){
  __shared__ int s[512];
  int t = threadIdx.x;
  int v = (t < nb) ? bsum[t] : 0;
  s[t] = v; __syncthreads();
  for (int o = 1; o < 512; o <<= 1){
    int a = (t >= o) ? s[t-o] : 0;
    __syncthreads();
    s[t] += a;
    __syncthreads();
  }
  if (t < nb) bsum[t] = s[t] - v;   // exclusive
}
__global__ void k_scan_write(const int* __restrict__ cnt, const int* __restrict__ bsum,
                             int n, int* __restrict__ rowp, int* __restrict__ cur){
  __shared__ int s[256];
  int t = threadIdx.x, i = blockIdx.x*256 + t;
  int v = (i < n) ? cnt[i] : 0;
  s[t] = v; __syncthreads();
  for (int o = 1; o < 256; o <<= 1){
    int a = (t >= o) ? s[t-o] : 0;
    __syncthreads();
    s[t] += a;
    __syncthreads();
  }
  if (i < n){
    int ex = bsum[blockIdx.x] + s[t] - v;
    rowp[i] = ex; cur[i] = ex;
  }
}

// ---------------- CSR fill ----------------
__global__ void k_fill_intra(const int* __restrict__ src, const int* __restrict__ dst,
                             const float* __restrict__ ea,
                             int* __restrict__ cur, int* __restrict__ col, float* __restrict__ val){
  int e = blockIdx.x*256 + threadIdx.x;
  if (e < EIN){
    int d = dst[e];
    int slot = atomicAdd(&cur[d], 1);
    col[slot] = src[e];
    val[slot] = ea[e];
  }
}
__global__ void k_fill_inter(const int* __restrict__ src, const int* __restrict__ dst,
                             const float* __restrict__ pos,
                             int* __restrict__ cur, int* __restrict__ col, float* __restrict__ val){
  int e = blockIdx.x*256 + threadIdx.x;
  if (e < EEX){
    int s = src[e], d = dst[e];
    float dx = pos[3*s+0] - pos[3*d+0];
    float dy = pos[3*s+1] - pos[3*d+1];
    float dz = pos[3*s+2] - pos[3*d+2];
    float w = expf(-(dx*dx + dy*dy + dz*dz));
    int slot = atomicAdd(&cur[d], 1);
    col[slot] = s;
    val[slot] = w;
  }
}

// ---------------- fused layer: gather(bf16) -> matmul(fp32) -> epilogue(bf16 state) ----------------
__global__ __launch_bounds__(256) void k_layer(
    const u16* __restrict__ hin, u16* __restrict__ hout,
    u16* __restrict__ vp, u16* __restrict__ vl,
    const int* __restrict__ rowI, const int* __restrict__ cntI,
    const int* __restrict__ colI, const float* __restrict__ valI,
    const int* __restrict__ rowE, const int* __restrict__ cntE,
    const int* __restrict__ colE, const float* __restrict__ valE,
    const float* __restrict__ WI, const float* __restrict__ bI,   // W: [k][j], coalesced
    const float* __restrict__ WE, const float* __restrict__ bE)
{
  __shared__ float aggI[TM][H];
  __shared__ float aggE[TM][H];
  const int n0 = blockIdx.x * TM;

  // ---- gather phase: thread = (slot 0..7 -> node, lane 0..31 -> 4 bf16 chans) ----
  {
    const int slot = threadIdx.x >> 5;
    const int lane = threadIdx.x & 31;
    const int j4 = lane * 4;
    const int n = n0 + slot;

    #pragma unroll
    for (int list = 0; list < 2; ++list){
      const int*   rowp = list ? rowE : rowI;
      const int*   cntp = list ? cntE : cntI;
      const int*   colp = list ? colE : colI;
      const float* valp = list ? valE : valI;
      float ax=0.f, ay=0.f, az=0.f, aw=0.f;
      const int s = rowp[n], c = cntp[n];
      int t = 0;
      for (; t + 8 <= c; t += 8){
        int cc[8]; float vv[8];
        #pragma unroll
        for (int u = 0; u < 8; ++u){ cc[u] = colp[s+t+u]; vv[u] = valp[s+t+u]; }
        ushort4 hh[8];
        #pragma unroll
        for (int u = 0; u < 8; ++u) hh[u] = *(const ushort4*)(hin + (size_t)cc[u]*H + j4);
        #pragma unroll
        for (int u = 0; u < 8; ++u){
          ax += bf2f(hh[u].x)*vv[u]; ay += bf2f(hh[u].y)*vv[u];
          az += bf2f(hh[u].z)*vv[u]; aw += bf2f(hh[u].w)*vv[u];
        }
      }
      for (; t + 4 <= c; t += 4){
        int cc[4]; float vv[4];
        #pragma unroll
        for (int u = 0; u < 4; ++u){ cc[u] = colp[s+t+u]; vv[u] = valp[s+t+u]; }
        ushort4 hh[4];
        #pragma unroll
        for (int u = 0; u < 4; ++u) hh[u] = *(const ushort4*)(hin + (size_t)cc[u]*H + j4);
        #pragma unroll
        for (int u = 0; u < 4; ++u){
          ax += bf2f(hh[u].x)*vv[u]; ay += bf2f(hh[u].y)*vv[u];
          az += bf2f(hh[u].z)*vv[u]; aw += bf2f(hh[u].w)*vv[u];
        }
      }
      for (; t < c; ++t){
        const int c0 = colp[s+t];
        const float v0 = valp[s+t];
        const ushort4 h0 = *(const ushort4*)(hin + (size_t)c0*H + j4);
        ax += bf2f(h0.x)*v0; ay += bf2f(h0.y)*v0; az += bf2f(h0.z)*v0; aw += bf2f(h0.w)*v0;
      }
      if (list) *(float4*)&aggE[slot][j4] = make_float4(ax, ay, az, aw);
      else      *(float4*)&aggI[slot][j4] = make_float4(ax, ay, az, aw);
    }
  }
  __syncthreads();

  // ---- matmul phase: thread = (j0 0..63, q 0..3 wave-uniform); 2 nodes x 2 cols ----
  const int j0 = threadIdx.x & 63;
  const int q  = threadIdx.x >> 6;
  float accI[2][2], accE[2][2];
  #pragma unroll
  for (int r = 0; r < 2; ++r){ accI[r][0]=accI[r][1]=accE[r][0]=accE[r][1]=0.f; }

  for (int kk = 0; kk < H; kk += 4){
    float aIb[2][4], aEb[2][4];
    #pragma unroll
    for (int r = 0; r < 2; ++r){
      const int m = q + 4*r;
      *(float4*)aIb[r] = *(const float4*)&aggI[m][kk];   // wave-uniform addr: LDS broadcast
      *(float4*)aEb[r] = *(const float4*)&aggE[m][kk];
    }
    #pragma unroll
    for (int k2 = 0; k2 < 4; ++k2){
      const int k = kk + k2;
      const float wi0 = WI[k*H + j0];
      const float wi1 = WI[k*H + j0 + 64];
      const float we0 = WE[k*H + j0];
      const float we1 = WE[k*H + j0 + 64];
      #pragma unroll
      for (int r = 0; r < 2; ++r){
        accI[r][0] += aIb[r][k2]*wi0;
        accI[r][1] += aIb[r][k2]*wi1;
        accE[r][0] += aEb[r][k2]*we0;
        accE[r][1] += aEb[r][k2]*we1;
      }
    }
  }

  // ---- epilogue: bf16 state read-modify-write ----
  #pragma unroll
  for (int r = 0; r < 2; ++r){
    const int m = q + 4*r;
    const int n = n0 + m;
    const float cI = (float)cntI[n];
    const float cE = (float)cntE[n];
    const float rdI = 1.0f / (cI + 1.0f);
    const float ldE = logf(cE + 1.0f);
    #pragma unroll
    for (int c2 = 0; c2 < 2; ++c2){
      const int j = j0 + 64*c2;
      const float mi = (accI[r][c2] + cI*bI[j]) * rdI;
      const float me = (accE[r][c2] + cE*bE[j]) * ldE;
      const size_t idx = (size_t)n*H + j;
      const float vpn = silu_f(mi + bf2f(vp[idx]));
      const float vln = silu_f(me + bf2f(vl[idx]));
      vp[idx] = f2bf(vpn); vl[idx] = f2bf(vln);
      hout[idx] = f2bf(bf2f(hin[idx]) + vpn + vln);
    }
  }
}

// ---------------- pool: batch is sorted; register-accumulate, flush on boundary ----------------
__global__ void k_pool(const u16* __restrict__ h, const int* __restrict__ batch,
                       float* __restrict__ g){
  const int j = threadIdx.x;
  const int n0 = blockIdx.x * 64;
  int nend = n0 + 64; if (nend > NN) nend = NN;
  float acc = 0.f;
  int cur = batch[n0];
  for (int n = n0; n < nend; ++n){
    int b = batch[n];
    if (b != cur){
      atomicAdd(&g[(size_t)cur*H + j], acc);
      acc = 0.f; cur = b;
    }
    acc += bf2f(h[(size_t)n*H + j]);
  }
  atomicAdd(&g[(size_t)cur*H + j], acc);
}

// ---------------- FC head: per-graph-row independent ----------------
__global__ void k_fc(const float* __restrict__ g, const float* __restrict__ fcW,
                     const float* __restrict__ fcb, const float* __restrict__ gamma,
                     const float* __restrict__ beta, const float* __restrict__ outW,
                     const float* __restrict__ outb, float* __restrict__ out){
  __shared__ float row[H];
  __shared__ float red[H];
  const int gi = blockIdx.x;
  const int j = threadIdx.x;
  row[j] = g[(size_t)gi*H + j];
  __syncthreads();
  const float bn_scale = rsqrtf(1.0f + 1e-5f);
  for (int l = 0; l < 3; ++l){
    const float* W = fcW + (size_t)l*H*H;
    float acc = fcb[l*H + j];
    #pragma unroll 8
    for (int k = 0; k < H; ++k) acc += row[k] * W[k*H + j];
    acc = (acc > 0.f) ? acc : 0.01f*acc;             // leaky_relu
    acc = acc * bn_scale * gamma[l*H + j] + beta[l*H + j];
    __syncthreads();
    row[j] = acc;
    __syncthreads();
  }
  red[j] = row[j] * outW[j];
  __syncthreads();
  for (int o = 64; o > 0; o >>= 1){
    if (j < o) red[j] += red[j + o];
    __syncthreads();
  }
  if (j == 0) out[gi] = red[0] + outb[0];
}

extern "C" void kernel_launch(void* const* d_in, const int* in_sizes, int n_in,
                              void* d_out, int out_size, void* d_ws, size_t ws_size,
                              hipStream_t stream)
{
  const float* x    = (const float*)d_in[0];
  const int*   eii  = (const int*)  d_in[1];
  const int*   eie  = (const int*)  d_in[2];
  const float* pos  = (const float*)d_in[3];
  const float* ea   = (const float*)d_in[4];
  const int*   batch= (const int*)  d_in[5];
  const float* lnW  = (const float*)d_in[6];
  const float* lnb  = (const float*)d_in[7];
  const float* WIa  = (const float*)d_in[8];
  const float* bIa  = (const float*)d_in[9];
  const float* WEa  = (const float*)d_in[10];
  const float* bEa  = (const float*)d_in[11];
  const float* fcW  = (const float*)d_in[12];
  const float* fcb  = (const float*)d_in[13];
  const float* gam  = (const float*)d_in[14];
  const float* bet  = (const float*)d_in[15];
  const float* outW = (const float*)d_in[16];
  const float* outb = (const float*)d_in[17];
  float* out = (float*)d_out;

  const int* src_i = eii;  const int* dst_i = eii + EIN;
  const int* src_e = eie;  const int* dst_e = eie + EEX;

  const size_t NH = (size_t)NN * H;
  // bf16 state buffers
  u16* hA = (u16*)d_ws;                    // NH
  u16* hB = hA + NH;
  u16* vp = hB + NH;
  u16* vl = vp + NH;
  float* gp = (float*)(vl + NH);           // NG*H
  int* cnt_i = (int*)(gp + (size_t)NG*H);  // NN
  int* cnt_e = cnt_i + NN;
  int* row_i = cnt_e + NN;
  int* row_e = row_i + NN;
  int* cur_i = row_e + NN;
  int* cur_e = cur_i + NN;
  int* col_i = cur_e + NN;                 // EIN
  float* val_i = (float*)(col_i + EIN);    // EIN
  int* col_e = (int*)(val_i + EIN);        // EEX
  float* val_e = (float*)(col_e + EEX);    // EEX
  int* bsum = (int*)(val_e + EEX);         // 1024

  const size_t need = 4*NH*sizeof(u16)
                    + ((size_t)NG*H + 6*(size_t)NN + 2*(size_t)EIN + 2*(size_t)EEX + 1024)*4;
  if (ws_size < need) return;

  // zero: vp+vl (contiguous bf16), gp+cnt_i+cnt_e (contiguous)
  hipMemsetAsync(vp, 0, 2*NH*sizeof(u16), stream);
  hipMemsetAsync(gp, 0, (size_t)NG*H*sizeof(float) + 2*(size_t)NN*sizeof(int), stream);

  k_lin_node<<<NN/TML, 256, 0, stream>>>(x, lnW, lnb, hA);

  k_count<<<(EIN+255)/256, 256, 0, stream>>>(dst_i, EIN, cnt_i);
  k_count<<<(EEX+255)/256, 256, 0, stream>>>(dst_e, EEX, cnt_e);

  const int NB = (NN + 255)/256;  // 391 <= 512
  k_block_sum<<<NB, 256, 0, stream>>>(cnt_i, NN, bsum);
  k_scan_top<<<1, 512, 0, stream>>>(bsum, NB);
  k_scan_write<<<NB, 256, 0, stream>>>(cnt_i, bsum, NN, row_i, cur_i);
  k_block_sum<<<NB, 256, 0, stream>>>(cnt_e, NN, bsum);
  k_scan_top<<<1, 512, 0, stream>>>(bsum, NB);
  k_scan_write<<<NB, 256, 0, stream>>>(cnt_e, bsum, NN, row_e, cur_e);

  k_fill_intra<<<(EIN+255)/256, 256, 0, stream>>>(src_i, dst_i, ea, cur_i, col_i, val_i);
  k_fill_inter<<<(EEX+255)/256, 256, 0, stream>>>(src_e, dst_e, pos, cur_e, col_e, val_e);

  const u16* hin = hA; u16* hout = hB;
  for (int l = 0; l < NL; ++l){
    k_layer<<<NN/TM, 256, 0, stream>>>(hin, hout, vp, vl,
        row_i, cnt_i, col_i, val_i,
        row_e, cnt_e, col_e, val_e,
        WIa + (size_t)l*H*H, bIa + (size_t)l*H,
        WEa + (size_t)l*H*H, bEa + (size_t)l*H);
    u16* t = (u16*)hin; hin = hout; hout = t;
  }
  // after 4 swaps final h is back in hA == hin

  k_pool<<<(NN+63)/64, H, 0, stream>>>(hin, batch, gp);
  k_fc<<<NG, H, 0, stream>>>(gp, fcW, fcb, gam, bet, outW, outb, out);
}

// Round 6
// 711.283 us; speedup vs baseline: 6.6763x; 1.8776x over previous
//
#include <hip/hip_runtime.h>
#include <math.h>

#define NN 100000
#define EIN 800000
#define EEX 400000
#define ND 35
#define H 128
#define NG 256
#define NL 4
#define TM 16          // nodes per block in k_layer (full MFMA M-tile)
#define TML 16         // nodes per block in k_lin_node

typedef unsigned short u16;
typedef short s8v __attribute__((ext_vector_type(8)));   // 8 bf16 (4 VGPRs)
typedef float f4v __attribute__((ext_vector_type(4)));   // 4 fp32 acc

__device__ __forceinline__ float silu_f(float x){ return x / (1.0f + expf(-x)); }
__device__ __forceinline__ float bf2f(u16 v){ return __uint_as_float(((unsigned)v) << 16); }
__device__ __forceinline__ u16 f2bf(float f){
  unsigned u = __float_as_uint(f);
  u += 0x7FFFu + ((u >> 16) & 1u);   // RNE
  return (u16)(u >> 16);
}

// ---------------- lin_node: h = silu(x @ W + b) -> bf16 ----------------
__global__ __launch_bounds__(256) void k_lin_node(const float* __restrict__ x,
                                                  const float* __restrict__ W,
                                                  const float* __restrict__ b,
                                                  u16* __restrict__ h){
  __shared__ float Ws[ND*H];      // 17.5 KB
  __shared__ float xs[TML*ND];
  const int n0 = blockIdx.x * TML;
  for (int i = threadIdx.x; i < ND*H; i += 256) Ws[i] = W[i];
  for (int i = threadIdx.x; i < TML*ND; i += 256) xs[i] = x[(size_t)n0*ND + i];
  __syncthreads();
  const int j = threadIdx.x & (H-1);
  const int half = threadIdx.x >> 7;
  const float bj = b[j];
  #pragma unroll
  for (int r = 0; r < TML/2; ++r){
    const int m = half + 2*r;
    float acc = bj;
    #pragma unroll
    for (int k = 0; k < ND; ++k) acc += xs[m*ND + k] * Ws[k*H + j];
    h[(size_t)(n0+m)*H + j] = f2bf(silu_f(acc));
  }
}

// ---------------- weight -> bf16 B-fragment swizzle (once per launch) ----------------
// Wfrag[((jt*4+kc)*64 + lane)*8 + r] = bf16(W[kc*32 + (lane>>4)*8 + r][jt*16 + (lane&15)])
__global__ void k_wfrag(const float* __restrict__ WI, const float* __restrict__ WE,
                        u16* __restrict__ WfI, u16* __restrict__ WfE){
  const int lm = blockIdx.x;            // 0..2*NL-1
  const int l = lm >> 1;
  const float* src = (lm & 1) ? (WE + (size_t)l*H*H) : (WI + (size_t)l*H*H);
  u16* dst = ((lm & 1) ? WfE : WfI) + (size_t)l*H*H;
  for (int idx = threadIdx.x; idx < H*H; idx += 256){
    const int r = idx & 7, lane = (idx>>3)&63, kc = (idx>>9)&3, jt = idx>>11;
    const int k = kc*32 + (lane>>4)*8 + r;
    const int j = jt*16 + (lane&15);
    dst[idx] = f2bf(src[k*H + j]);
  }
}

// ---------------- degree count ----------------
__global__ void k_count(const int* __restrict__ dst, int ne, int* __restrict__ cnt){
  int e = blockIdx.x*256 + threadIdx.x;
  if (e < ne) atomicAdd(&cnt[dst[e]], 1);
}

// ---------------- 2-level exclusive scan over N counts ----------------
__global__ void k_block_sum(const int* __restrict__ cnt, int n, int* __restrict__ bsum){
  __shared__ int s[256];
  int i = blockIdx.x*256 + threadIdx.x;
  s[threadIdx.x] = (i < n) ? cnt[i] : 0;
  __syncthreads();
  for (int o = 128; o > 0; o >>= 1){
    if (threadIdx.x < o) s[threadIdx.x] += s[threadIdx.x + o];
    __syncthreads();
  }
  if (threadIdx.x == 0) bsum[blockIdx.x] = s[0];
}
__global__ void k_scan_top(int* __restrict__ bsum, int nb){
  __shared__ int s[512];
  int t = threadIdx.x;
  int v = (t < nb) ? bsum[t] : 0;
  s[t] = v; __syncthreads();
  for (int o = 1; o < 512; o <<= 1){
    int a = (t >= o) ? s[t-o] : 0;
    __syncthreads();
    s[t] += a;
    __syncthreads();
  }
  if (t < nb) bsum[t] = s[t] - v;   // exclusive
}
__global__ void k_scan_write(const int* __restrict__ cnt, const int* __restrict__ bsum,
                             int n, int* __restrict__ rowp, int* __restrict__ cur){
  __shared__ int s[256];
  int t = threadIdx.x, i = blockIdx.x*256 + t;
  int v = (i < n) ? cnt[i] : 0;
  s[t] = v; __syncthreads();
  for (int o = 1; o < 256; o <<= 1){
    int a = (t >= o) ? s[t-o] : 0;
    __syncthreads();
    s[t] += a;
    __syncthreads();
  }
  if (i < n){
    int ex = bsum[blockIdx.x] + s[t] - v;
    rowp[i] = ex; cur[i] = ex;
  }
}

// ---------------- CSR fill ----------------
__global__ void k_fill_intra(const int* __restrict__ src, const int* __restrict__ dst,
                             const float* __restrict__ ea,
                             int* __restrict__ cur, int* __restrict__ col, float* __restrict__ val){
  int e = blockIdx.x*256 + threadIdx.x;
  if (e < EIN){
    int d = dst[e];
    int slot = atomicAdd(&cur[d], 1);
    col[slot] = src[e];
    val[slot] = ea[e];
  }
}
__global__ void k_fill_inter(const int* __restrict__ src, const int* __restrict__ dst,
                             const float* __restrict__ pos,
                             int* __restrict__ cur, int* __restrict__ col, float* __restrict__ val){
  int e = blockIdx.x*256 + threadIdx.x;
  if (e < EEX){
    int s = src[e], d = dst[e];
    float dx = pos[3*s+0] - pos[3*d+0];
    float dy = pos[3*s+1] - pos[3*d+1];
    float dz = pos[3*s+2] - pos[3*d+2];
    float w = expf(-(dx*dx + dy*dy + dz*dz));
    int slot = atomicAdd(&cur[d], 1);
    col[slot] = s;
    val[slot] = w;
  }
}

// ---------------- fused layer: gather(bf16) -> MFMA matmul -> epilogue ----------------
__global__ __launch_bounds__(256) void k_layer(
    const u16* __restrict__ hin, u16* __restrict__ hout,
    u16* __restrict__ vp, u16* __restrict__ vl,
    const int* __restrict__ rowI, const int* __restrict__ cntI,
    const int* __restrict__ colI, const float* __restrict__ valI,
    const int* __restrict__ rowE, const int* __restrict__ cntE,
    const int* __restrict__ colE, const float* __restrict__ valE,
    const u16* __restrict__ WfI, const float* __restrict__ bI,   // B-fragment order, bf16
    const u16* __restrict__ WfE, const float* __restrict__ bE)
{
  // A-operand layout (m120-verified): A[m=lane&15][k=quad*8+j]; rows padded to 136 to spread banks
  __shared__ u16 aggIs[TM][136];
  __shared__ u16 aggEs[TM][136];
  const int n0 = blockIdx.x * TM;
  const int tid = threadIdx.x;

  // ---- gather phase: thread = (slot 0..15 -> node, l16 0..15 -> 8 bf16 chans) ----
  {
    const int slot = tid >> 4;
    const int l16  = tid & 15;
    const int j8 = l16 * 8;
    const int n = n0 + slot;

    #pragma unroll
    for (int list = 0; list < 2; ++list){
      const int*   rowp = list ? rowE : rowI;
      const int*   cntp = list ? cntE : cntI;
      const int*   colp = list ? colE : colI;
      const float* valp = list ? valE : valI;
      float a[8];
      #pragma unroll
      for (int u = 0; u < 8; ++u) a[u] = 0.f;
      const int s = rowp[n], c = cntp[n];
      int t = 0;
      for (; t + 4 <= c; t += 4){
        int cc[4]; float vv[4];
        #pragma unroll
        for (int u = 0; u < 4; ++u){ cc[u] = colp[s+t+u]; vv[u] = valp[s+t+u]; }
        uint4 hh[4];
        #pragma unroll
        for (int u = 0; u < 4; ++u) hh[u] = *(const uint4*)(hin + (size_t)cc[u]*H + j8);
        #pragma unroll
        for (int u = 0; u < 4; ++u){
          a[0] += __uint_as_float(hh[u].x << 16)          * vv[u];
          a[1] += __uint_as_float(hh[u].x & 0xffff0000u)  * vv[u];
          a[2] += __uint_as_float(hh[u].y << 16)          * vv[u];
          a[3] += __uint_as_float(hh[u].y & 0xffff0000u)  * vv[u];
          a[4] += __uint_as_float(hh[u].z << 16)          * vv[u];
          a[5] += __uint_as_float(hh[u].z & 0xffff0000u)  * vv[u];
          a[6] += __uint_as_float(hh[u].w << 16)          * vv[u];
          a[7] += __uint_as_float(hh[u].w & 0xffff0000u)  * vv[u];
        }
      }
      for (; t < c; ++t){
        const int c0 = colp[s+t];
        const float v0 = valp[s+t];
        const uint4 h0 = *(const uint4*)(hin + (size_t)c0*H + j8);
        a[0] += __uint_as_float(h0.x << 16)         * v0;
        a[1] += __uint_as_float(h0.x & 0xffff0000u) * v0;
        a[2] += __uint_as_float(h0.y << 16)         * v0;
        a[3] += __uint_as_float(h0.y & 0xffff0000u) * v0;
        a[4] += __uint_as_float(h0.z << 16)         * v0;
        a[5] += __uint_as_float(h0.z & 0xffff0000u) * v0;
        a[6] += __uint_as_float(h0.w << 16)         * v0;
        a[7] += __uint_as_float(h0.w & 0xffff0000u) * v0;
      }
      const unsigned p0 = (unsigned)f2bf(a[0]) | ((unsigned)f2bf(a[1]) << 16);
      const unsigned p1 = (unsigned)f2bf(a[2]) | ((unsigned)f2bf(a[3]) << 16);
      const unsigned p2 = (unsigned)f2bf(a[4]) | ((unsigned)f2bf(a[5]) << 16);
      const unsigned p3 = (unsigned)f2bf(a[6]) | ((unsigned)f2bf(a[7]) << 16);
      u16* drow = list ? &aggEs[slot][j8] : &aggIs[slot][j8];
      *(uint4*)drow = make_uint4(p0, p1, p2, p3);
    }
  }
  __syncthreads();

  // ---- MFMA phase: wave w owns j-tiles {2w, 2w+1} for BOTH mats ----
  const int lane = tid & 63;
  const int w    = tid >> 6;
  const int jta = 2*w, jtb = 2*w + 1;
  const int col  = lane & 15;
  const int quad = lane >> 4;

  f4v accIA = {0.f,0.f,0.f,0.f}, accIB = {0.f,0.f,0.f,0.f};
  f4v accEA = {0.f,0.f,0.f,0.f}, accEB = {0.f,0.f,0.f,0.f};

  #pragma unroll
  for (int kc = 0; kc < 4; ++kc){
    const int koff = kc*32 + quad*8;
    const s8v aI = *(const s8v*)&aggIs[col][koff];
    const s8v aE = *(const s8v*)&aggEs[col][koff];
    const s8v bIA = *(const s8v*)(WfI + (((jta*4 + kc)*64 + lane) << 3));
    const s8v bIB = *(const s8v*)(WfI + (((jtb*4 + kc)*64 + lane) << 3));
    const s8v bEA = *(const s8v*)(WfE + (((jta*4 + kc)*64 + lane) << 3));
    const s8v bEB = *(const s8v*)(WfE + (((jtb*4 + kc)*64 + lane) << 3));
    accIA = __builtin_amdgcn_mfma_f32_16x16x32_bf16(aI, bIA, accIA, 0, 0, 0);
    accIB = __builtin_amdgcn_mfma_f32_16x16x32_bf16(aI, bIB, accIB, 0, 0, 0);
    accEA = __builtin_amdgcn_mfma_f32_16x16x32_bf16(aE, bEA, accEA, 0, 0, 0);
    accEB = __builtin_amdgcn_mfma_f32_16x16x32_bf16(aE, bEB, accEB, 0, 0, 0);
  }

  // ---- epilogue: C/D layout col=lane&15, row=quad*4+reg (m89-verified) ----
  #pragma unroll
  for (int r = 0; r < 4; ++r){
    const int m = quad*4 + r;
    const int n = n0 + m;
    const float cI = (float)cntI[n];
    const float cE = (float)cntE[n];
    const float rdI = 1.0f / (cI + 1.0f);
    const float ldE = logf(cE + 1.0f);
    #pragma unroll
    for (int half = 0; half < 2; ++half){
      const int j = (half ? jtb : jta)*16 + col;
      const float aIv = half ? accIB[r] : accIA[r];
      const float aEv = half ? accEB[r] : accEA[r];
      const float mi = (aIv + cI*bI[j]) * rdI;
      const float me = (aEv + cE*bE[j]) * ldE;
      const size_t idx = (size_t)n*H + j;
      const float vpn = silu_f(mi + bf2f(vp[idx]));
      const float vln = silu_f(me + bf2f(vl[idx]));
      vp[idx] = f2bf(vpn); vl[idx] = f2bf(vln);
      hout[idx] = f2bf(bf2f(hin[idx]) + vpn + vln);
    }
  }
}

// ---------------- pool: batch is sorted; register-accumulate, flush on boundary ----------------
__global__ void k_pool(const u16* __restrict__ h, const int* __restrict__ batch,
                       float* __restrict__ g){
  const int j = threadIdx.x;
  const int n0 = blockIdx.x * 64;
  int nend = n0 + 64; if (nend > NN) nend = NN;
  float acc = 0.f;
  int cur = batch[n0];
  for (int n = n0; n < nend; ++n){
    int b = batch[n];
    if (b != cur){
      atomicAdd(&g[(size_t)cur*H + j], acc);
      acc = 0.f; cur = b;
    }
    acc += bf2f(h[(size_t)n*H + j]);
  }
  atomicAdd(&g[(size_t)cur*H + j], acc);
}

// ---------------- FC head: per-graph-row independent ----------------
__global__ void k_fc(const float* __restrict__ g, const float* __restrict__ fcW,
                     const float* __restrict__ fcb, const float* __restrict__ gamma,
                     const float* __restrict__ beta, const float* __restrict__ outW,
                     const float* __restrict__ outb, float* __restrict__ out){
  __shared__ float row[H];
  __shared__ float red[H];
  const int gi = blockIdx.x;
  const int j = threadIdx.x;
  row[j] = g[(size_t)gi*H + j];
  __syncthreads();
  const float bn_scale = rsqrtf(1.0f + 1e-5f);
  for (int l = 0; l < 3; ++l){
    const float* W = fcW + (size_t)l*H*H;
    float acc = fcb[l*H + j];
    #pragma unroll 8
    for (int k = 0; k < H; ++k) acc += row[k] * W[k*H + j];
    acc = (acc > 0.f) ? acc : 0.01f*acc;             // leaky_relu
    acc = acc * bn_scale * gamma[l*H + j] + beta[l*H + j];
    __syncthreads();
    row[j] = acc;
    __syncthreads();
  }
  red[j] = row[j] * outW[j];
  __syncthreads();
  for (int o = 64; o > 0; o >>= 1){
    if (j < o) red[j] += red[j + o];
    __syncthreads();
  }
  if (j == 0) out[gi] = red[0] + outb[0];
}

extern "C" void kernel_launch(void* const* d_in, const int* in_sizes, int n_in,
                              void* d_out, int out_size, void* d_ws, size_t ws_size,
                              hipStream_t stream)
{
  const float* x    = (const float*)d_in[0];
  const int*   eii  = (const int*)  d_in[1];
  const int*   eie  = (const int*)  d_in[2];
  const float* pos  = (const float*)d_in[3];
  const float* ea   = (const float*)d_in[4];
  const int*   batch= (const int*)  d_in[5];
  const float* lnW  = (const float*)d_in[6];
  const float* lnb  = (const float*)d_in[7];
  const float* WIa  = (const float*)d_in[8];
  const float* bIa  = (const float*)d_in[9];
  const float* WEa  = (const float*)d_in[10];
  const float* bEa  = (const float*)d_in[11];
  const float* fcW  = (const float*)d_in[12];
  const float* fcb  = (const float*)d_in[13];
  const float* gam  = (const float*)d_in[14];
  const float* bet  = (const float*)d_in[15];
  const float* outW = (const float*)d_in[16];
  const float* outb = (const float*)d_in[17];
  float* out = (float*)d_out;

  const int* src_i = eii;  const int* dst_i = eii + EIN;
  const int* src_e = eie;  const int* dst_e = eie + EEX;

  const size_t NH = (size_t)NN * H;
  // bf16 state buffers
  u16* hA = (u16*)d_ws;                    // NH
  u16* hB = hA + NH;
  u16* vp = hB + NH;
  u16* vl = vp + NH;
  float* gp = (float*)(vl + NH);           // NG*H
  int* cnt_i = (int*)(gp + (size_t)NG*H);  // NN
  int* cnt_e = cnt_i + NN;
  int* row_i = cnt_e + NN;
  int* row_e = row_i + NN;
  int* cur_i = row_e + NN;
  int* cur_e = cur_i + NN;
  int* col_i = cur_e + NN;                 // EIN
  float* val_i = (float*)(col_i + EIN);    // EIN
  int* col_e = (int*)(val_i + EIN);        // EEX
  float* val_e = (float*)(col_e + EEX);    // EEX
  int* bsum = (int*)(val_e + EEX);         // 1024
  u16* WfI = (u16*)(bsum + 1024);          // NL*H*H bf16, 16B-aligned
  u16* WfE = WfI + (size_t)NL*H*H;         // NL*H*H bf16

  const size_t need = 4*NH*sizeof(u16)
                    + ((size_t)NG*H + 6*(size_t)NN + 2*(size_t)EIN + 2*(size_t)EEX + 1024)*4
                    + 2*(size_t)NL*H*H*sizeof(u16);
  if (ws_size < need) return;

  // zero: vp+vl (contiguous bf16), gp+cnt_i+cnt_e (contiguous)
  hipMemsetAsync(vp, 0, 2*NH*sizeof(u16), stream);
  hipMemsetAsync(gp, 0, (size_t)NG*H*sizeof(float) + 2*(size_t)NN*sizeof(int), stream);

  k_wfrag<<<2*NL, 256, 0, stream>>>(WIa, WEa, WfI, WfE);
  k_lin_node<<<NN/TML, 256, 0, stream>>>(x, lnW, lnb, hA);

  k_count<<<(EIN+255)/256, 256, 0, stream>>>(dst_i, EIN, cnt_i);
  k_count<<<(EEX+255)/256, 256, 0, stream>>>(dst_e, EEX, cnt_e);

  const int NB = (NN + 255)/256;  // 391 <= 512
  k_block_sum<<<NB, 256, 0, stream>>>(cnt_i, NN, bsum);
  k_scan_top<<<1, 512, 0, stream>>>(bsum, NB);
  k_scan_write<<<NB, 256, 0, stream>>>(cnt_i, bsum, NN, row_i, cur_i);
  k_block_sum<<<NB, 256, 0, stream>>>(cnt_e, NN, bsum);
  k_scan_top<<<1, 512, 0, stream>>>(bsum, NB);
  k_scan_write<<<NB, 256, 0, stream>>>(cnt_e, bsum, NN, row_e, cur_e);

  k_fill_intra<<<(EIN+255)/256, 256, 0, stream>>>(src_i, dst_i, ea, cur_i, col_i, val_i);
  k_fill_inter<<<(EEX+255)/256, 256, 0, stream>>>(src_e, dst_e, pos, cur_e, col_e, val_e);

  const u16* hin = hA; u16* hout = hB;
  for (int l = 0; l < NL; ++l){
    k_layer<<<NN/TM, 256, 0, stream>>>(hin, hout, vp, vl,
        row_i, cnt_i, col_i, val_i,
        row_e, cnt_e, col_e, val_e,
        WfI + (size_t)l*H*H, bIa + (size_t)l*H,
        WfE + (size_t)l*H*H, bEa + (size_t)l*H);
    u16* t = (u16*)hin; hin = hout; hout = t;
  }
  // after 4 swaps final h is back in hA == hin

  k_pool<<<(NN+63)/64, H, 0, stream>>>(hin, batch, gp);
  k_fc<<<NG, H, 0, stream>>>(gp, fcW, fcb, gam, bet, outW, outb, out);
}